// Round 21
// baseline (51.806 us; speedup 1.0000x reference)
//
#include <hip/hip_runtime.h>
#include <hip/hip_bf16.h>

#define HH 192
#define WW 192
#define HOUT 190
#define NCH 64
#define W2_N (64 * 9 * 64)

typedef __attribute__((ext_vector_type(8))) short bf16x8;
typedef __attribute__((ext_vector_type(4))) float f32x4;

static __device__ __forceinline__ ushort f2bf(float f) {
    __hip_bfloat16 h = __float2bfloat16(f);   // RNE
    return *reinterpret_cast<ushort*>(&h);
}

// W2[o][tap][c] = sum_t (conn[o*16+t]==c) * w[(o*16+t)*9 + tap], bf16.
__global__ __launch_bounds__(256) void build_w2(const float* __restrict__ w,
                                                const int* __restrict__ conn,
                                                ushort* __restrict__ w2) {
    int idx = blockIdx.x * 256 + threadIdx.x;
    if (idx >= W2_N) return;
    int o = idx / 576, rem = idx - o * 576, tap = rem >> 6, c = rem & 63;
    float s = 0.f;
    #pragma unroll
    for (int t = 0; t < 16; ++t) {
        int k = o * 16 + t;
        if (conn[k] == c) s += w[k * 9 + tap];
    }
    w2[idx] = f2bf(s);
}

// Dense 64->64 3x3 conv via mfma_f32_16x16x32_bf16, tap-outer implicit GEMM.
// Block: 8 output rows x 16 cols x 64 outch. 4 waves, wave w = outch 16w..16w+15.
// LDS x-tile: [10 rows][18 cols][72 ch-slots] bf16 (col stride 144 B).
// Key R21 changes: launch_bounds(256,2) for VGPR headroom; W2 B-frags hoisted
// to 72 registers BEFORE staging (latency hidden under staging); per-(s,kw)
// batched ds_reads fenced from the MFMA cluster.
__global__ __launch_bounds__(256, 2) void scm_mfma(
    const float* __restrict__ x,
    const ushort* __restrict__ w2,
    const float* __restrict__ bias,
    float* __restrict__ out)
{
    __shared__ ushort xt[10 * 18 * 72];   // 25,920 B

    const int tid  = threadIdx.x;
    const int lane = tid & 63;
    const int wv   = tid >> 6;
    const int col  = lane & 15;           // A-frag m (pixel col) / B-frag n
    const int g    = lane >> 4;           // k-subgroup

    // Flattened grid (1152) + bijective XCD swizzle (1152 % 8 == 0):
    // consecutive logical ids share an XCD -> x row-band reuse in its L2.
    const int bid = blockIdx.x;
    const int lid = (bid & 7) * 144 + (bid >> 3);
    const int b      = lid / 288;
    const int tileid = lid % 288;
    const int ti0 = (tileid / 12) * 8;    // 24 row tiles
    const int tj0 = (tileid % 12) * 16;   // 12 col tiles

    // ---- B hoist: all 18 W2 fragments into registers, issued first.
    const ushort* bp = w2 + (16 * wv + col) * 576 + g * 8;
    bf16x8 Bf[9][2];
    #pragma unroll
    for (int tap = 0; tap < 9; ++tap)
        #pragma unroll
        for (int s = 0; s < 2; ++s)
            Bf[tap][s] = *(const bf16x8*)(bp + tap * 64 + s * 32);

    // ---- staging: spatial-lane gather, wave-sliced channels.
    // Loads unconditional (clamped addrs) so they pipeline; writes masked.
    {
        const int srr  = lane / 18;       // 0..2 (lanes 54..63: writes masked)
        const int scol = lane - srr * 18; // 0..17
        const bool act = lane < 54;
        int gc = tj0 + scol; if (gc > 191) gc = 191;
        int gr0 = ti0 + srr;     if (gr0 > 191) gr0 = 191;   // lrow = srr
        int gr1 = ti0 + srr + 3; if (gr1 > 191) gr1 = 191;   // lrow = srr+3
        int gr2 = ti0 + srr + 6; if (gr2 > 191) gr2 = 191;   // lrow = srr+6
        int gr3 = ti0 + srr + 9; if (gr3 > 191) gr3 = 191;   // lrow = srr+9 (<10 only srr==0)
        #pragma unroll
        for (int j = 0; j < 16; ++j) {
            const int c = wv * 16 + j;    // wave-uniform channel
            const float* xc = x + ((size_t)(b * NCH + c)) * (HH * WW);
            float v0 = xc[gr0 * WW + gc];
            float v1 = xc[gr1 * WW + gc];
            float v2 = xc[gr2 * WW + gc];
            float v3 = xc[gr3 * WW + gc];
            if (act) {
                xt[((srr    ) * 18 + scol) * 72 + c] = f2bf(v0);
                xt[((srr + 3) * 18 + scol) * 72 + c] = f2bf(v1);
                xt[((srr + 6) * 18 + scol) * 72 + c] = f2bf(v2);
                if (srr == 0)
                    xt[(9 * 18 + scol) * 72 + c] = f2bf(v3);
            }
        }
    }
    __syncthreads();

    // ---- compute
    f32x4 acc[8];
    #pragma unroll
    for (int i = 0; i < 8; ++i) acc[i] = (f32x4){0.f, 0.f, 0.f, 0.f};

    const ushort* ap0 = &xt[col * 72 + g * 8];

    #pragma unroll
    for (int s = 0; s < 2; ++s) {
        #pragma unroll
        for (int kw = 0; kw < 3; ++kw) {
            bf16x8 f[10];
            #pragma unroll
            for (int R = 0; R < 10; ++R)
                f[R] = *(const bf16x8*)(ap0 + (R * 18 + kw) * 72 + s * 32);
            __builtin_amdgcn_sched_barrier(0);   // loads clustered before MFMAs
            #pragma unroll
            for (int Mt = 0; Mt < 8; ++Mt) {
                acc[Mt] = __builtin_amdgcn_mfma_f32_16x16x32_bf16(f[Mt],     Bf[kw][s],     acc[Mt], 0, 0, 0);
                acc[Mt] = __builtin_amdgcn_mfma_f32_16x16x32_bf16(f[Mt + 1], Bf[3 + kw][s], acc[Mt], 0, 0, 0);
                acc[Mt] = __builtin_amdgcn_mfma_f32_16x16x32_bf16(f[Mt + 2], Bf[6 + kw][s], acc[Mt], 0, 0, 0);
            }
        }
    }

    // ---- epilogue: D row = 4g+reg -> pixel col tj0+4g+reg; D col = lane&15 -> o.
    const int o = 16 * wv + col;
    const float bv = bias[o];
    #pragma unroll
    for (int Mt = 0; Mt < 8; ++Mt) {
        int row = ti0 + Mt;
        if (row < HOUT) {
            int cj = tj0 + 4 * g;
            float* rp = out + ((size_t)(b * NCH + o) * HOUT + row) * HOUT + cj;
            float v0 = acc[Mt][0] + bv, v1 = acc[Mt][1] + bv;
            float v2 = acc[Mt][2] + bv, v3 = acc[Mt][3] + bv;
            if (cj + 3 < HOUT) {
                *(float2*)(rp)     = make_float2(v0, v1);
                *(float2*)(rp + 2) = make_float2(v2, v3);
            } else {
                if (cj     < HOUT) rp[0] = v0;
                if (cj + 1 < HOUT) rp[1] = v1;
                if (cj + 2 < HOUT) rp[2] = v2;
                if (cj + 3 < HOUT) rp[3] = v3;
            }
        }
    }
}

extern "C" void kernel_launch(void* const* d_in, const int* in_sizes, int n_in,
                              void* d_out, int out_size, void* d_ws, size_t ws_size,
                              hipStream_t stream) {
    const float* x       = (const float*)d_in[0];
    const float* weight  = (const float*)d_in[1];
    const float* bias    = (const float*)d_in[2];
    const int*   conn_in = (const int*)d_in[3];
    // d_in[4] = conn_out (implicit: k -> k/16)

    ushort* w2 = (ushort*)d_ws;   // 73,728 B

    build_w2<<<dim3((W2_N + 255) / 256), dim3(256), 0, stream>>>(weight, conn_in, w2);

    scm_mfma<<<dim3(1152), dim3(256), 0, stream>>>(x, w2, bias, (float*)d_out);
}

// Round 22
// 34.883 us; speedup vs baseline: 1.4851x; 1.4851x over previous
//
#include <hip/hip_runtime.h>
#include <hip/hip_bf16.h>

#define HH 192
#define WW 192
#define HOUT 190
#define NCH 64
#define W2_N (64 * 9 * 64)

typedef __attribute__((ext_vector_type(8))) short bf16x8;
typedef __attribute__((ext_vector_type(4))) float f32x4;

static __device__ __forceinline__ ushort f2bf(float f) {
    __hip_bfloat16 h = __float2bfloat16(f);   // RNE
    return *reinterpret_cast<ushort*>(&h);
}

// W2[o][tap][c] = sum_t (conn[o*16+t]==c) * w[(o*16+t)*9 + tap], bf16.
__global__ __launch_bounds__(256) void build_w2(const float* __restrict__ w,
                                                const int* __restrict__ conn,
                                                ushort* __restrict__ w2) {
    int idx = blockIdx.x * 256 + threadIdx.x;
    if (idx >= W2_N) return;
    int o = idx / 576, rem = idx - o * 576, tap = rem >> 6, c = rem & 63;
    float s = 0.f;
    #pragma unroll
    for (int t = 0; t < 16; ++t) {
        int k = o * 16 + t;
        if (conn[k] == c) s += w[k * 9 + tap];
    }
    w2[idx] = f2bf(s);
}

// Dense 64->64 3x3 conv via mfma_f32_16x16x32_bf16, tap-outer implicit GEMM.
// R22: OPERAND-SWAPPED — A = W2 (M=o), B = x (N=pixel col), so D's lane dim
// is the contiguous pixel column: stores are 4x64B segments per instruction
// instead of 64x8B channel-scatter. Fragments/ds_reads identical to R21.
__global__ __launch_bounds__(256, 2) void scm_mfma(
    const float* __restrict__ x,
    const ushort* __restrict__ w2,
    const float* __restrict__ bias,
    float* __restrict__ out)
{
    __shared__ ushort xt[10 * 18 * 72];   // 25,920 B

    const int tid  = threadIdx.x;
    const int lane = tid & 63;
    const int wv   = tid >> 6;
    const int col  = lane & 15;           // B-frag n (pixel col) / A-frag m (o)
    const int g    = lane >> 4;           // k-subgroup

    // Flattened grid (1152) + bijective XCD swizzle (1152 % 8 == 0).
    const int bid = blockIdx.x;
    const int lid = (bid & 7) * 144 + (bid >> 3);
    const int b      = lid / 288;
    const int tileid = lid % 288;
    const int ti0 = (tileid / 12) * 8;    // 24 row tiles
    const int tj0 = (tileid % 12) * 16;   // 12 col tiles

    // ---- W2 A-fragments into registers, issued first (fly under staging).
    const ushort* bp = w2 + (16 * wv + col) * 576 + g * 8;
    bf16x8 Bf[9][2];
    #pragma unroll
    for (int tap = 0; tap < 9; ++tap)
        #pragma unroll
        for (int s = 0; s < 2; ++s)
            Bf[tap][s] = *(const bf16x8*)(bp + tap * 64 + s * 32);

    // ---- staging: spatial-lane gather, wave-sliced channels.
    // ALL 64 loads issued into registers first (one vmcnt drain), then writes.
    {
        const int srr  = lane / 18;       // 0..2 (lanes 54..63: writes masked)
        const int scol = lane - srr * 18; // 0..17
        const bool act = lane < 54;
        int gc = tj0 + scol; if (gc > 191) gc = 191;
        int gr0 = ti0 + srr;     if (gr0 > 191) gr0 = 191;
        int gr1 = ti0 + srr + 3; if (gr1 > 191) gr1 = 191;
        int gr2 = ti0 + srr + 6; if (gr2 > 191) gr2 = 191;
        int gr3 = ti0 + srr + 9; if (gr3 > 191) gr3 = 191;

        float vals[16][4];
        #pragma unroll
        for (int j = 0; j < 16; ++j) {
            const int c = wv * 16 + j;
            const float* xc = x + ((size_t)(b * NCH + c)) * (HH * WW);
            vals[j][0] = xc[gr0 * WW + gc];
            vals[j][1] = xc[gr1 * WW + gc];
            vals[j][2] = xc[gr2 * WW + gc];
            vals[j][3] = xc[gr3 * WW + gc];
        }
        __builtin_amdgcn_sched_barrier(0);
        if (act) {
            #pragma unroll
            for (int j = 0; j < 16; ++j) {
                const int c = wv * 16 + j;
                xt[((srr    ) * 18 + scol) * 72 + c] = f2bf(vals[j][0]);
                xt[((srr + 3) * 18 + scol) * 72 + c] = f2bf(vals[j][1]);
                xt[((srr + 6) * 18 + scol) * 72 + c] = f2bf(vals[j][2]);
                if (srr == 0)
                    xt[(9 * 18 + scol) * 72 + c] = f2bf(vals[j][3]);
            }
        }
    }
    __syncthreads();

    // ---- compute (operands SWAPPED vs R21: acc = mfma(W2frag, xfrag, acc))
    f32x4 acc[8];
    #pragma unroll
    for (int i = 0; i < 8; ++i) acc[i] = (f32x4){0.f, 0.f, 0.f, 0.f};

    const ushort* ap0 = &xt[col * 72 + g * 8];

    #pragma unroll
    for (int s = 0; s < 2; ++s) {
        #pragma unroll
        for (int kw = 0; kw < 3; ++kw) {
            bf16x8 f[10];
            #pragma unroll
            for (int R = 0; R < 10; ++R)
                f[R] = *(const bf16x8*)(ap0 + (R * 18 + kw) * 72 + s * 32);
            __builtin_amdgcn_sched_barrier(0);   // loads clustered before MFMAs
            #pragma unroll
            for (int Mt = 0; Mt < 8; ++Mt) {
                acc[Mt] = __builtin_amdgcn_mfma_f32_16x16x32_bf16(Bf[kw][s],     f[Mt],     acc[Mt], 0, 0, 0);
                acc[Mt] = __builtin_amdgcn_mfma_f32_16x16x32_bf16(Bf[3 + kw][s], f[Mt + 1], acc[Mt], 0, 0, 0);
                acc[Mt] = __builtin_amdgcn_mfma_f32_16x16x32_bf16(Bf[6 + kw][s], f[Mt + 2], acc[Mt], 0, 0, 0);
            }
        }
    }

    // ---- epilogue: D col = lane&15 = pixel col (contiguous); D row = o-quad.
    // Lane writes o = 16wv + 4g + reg at pixel (ti0+Mt, tj0+col).
    const int pcol = tj0 + col;
    const int obase = 16 * wv + 4 * g;
    float bv[4];
    #pragma unroll
    for (int reg = 0; reg < 4; ++reg) bv[reg] = bias[obase + reg];

    if (pcol < HOUT) {
        #pragma unroll
        for (int Mt = 0; Mt < 8; ++Mt) {
            const int row = ti0 + Mt;
            if (row < HOUT) {
                float* rp = out + ((size_t)(b * NCH + obase) * HOUT + row) * HOUT + pcol;
                #pragma unroll
                for (int reg = 0; reg < 4; ++reg)
                    rp[(size_t)reg * HOUT * HOUT] = acc[Mt][reg] + bv[reg];
            }
        }
    }
}

extern "C" void kernel_launch(void* const* d_in, const int* in_sizes, int n_in,
                              void* d_out, int out_size, void* d_ws, size_t ws_size,
                              hipStream_t stream) {
    const float* x       = (const float*)d_in[0];
    const float* weight  = (const float*)d_in[1];
    const float* bias    = (const float*)d_in[2];
    const int*   conn_in = (const int*)d_in[3];
    // d_in[4] = conn_out (implicit: k -> k/16)

    ushort* w2 = (ushort*)d_ws;   // 73,728 B

    build_w2<<<dim3((W2_N + 255) / 256), dim3(256), 0, stream>>>(weight, conn_in, w2);

    scm_mfma<<<dim3(1152), dim3(256), 0, stream>>>(x, w2, bias, (float*)d_out);
}

// Round 23
// 34.554 us; speedup vs baseline: 1.4993x; 1.0095x over previous
//
#include <hip/hip_runtime.h>
#include <hip/hip_bf16.h>

#define HH 192
#define WW 192
#define HOUT 190
#define NCH 64
#define W2_N (64 * 9 * 64)

typedef __attribute__((ext_vector_type(8))) short bf16x8;
typedef __attribute__((ext_vector_type(4))) float f32x4;

static __device__ __forceinline__ ushort f2bf(float f) {
    __hip_bfloat16 h = __float2bfloat16(f);   // RNE
    return *reinterpret_cast<ushort*>(&h);
}
static __device__ __forceinline__ uint pack2bf(float lo, float hi) {
    return (uint)f2bf(lo) | ((uint)f2bf(hi) << 16);
}

// W2[o][tap][c] = sum_t (conn[o*16+t]==c) * w[(o*16+t)*9 + tap], bf16.
__global__ __launch_bounds__(256) void build_w2(const float* __restrict__ w,
                                                const int* __restrict__ conn,
                                                ushort* __restrict__ w2) {
    int idx = blockIdx.x * 256 + threadIdx.x;
    if (idx >= W2_N) return;
    int o = idx / 576, rem = idx - o * 576, tap = rem >> 6, c = rem & 63;
    float s = 0.f;
    #pragma unroll
    for (int t = 0; t < 16; ++t) {
        int k = o * 16 + t;
        if (conn[k] == c) s += w[k * 9 + tap];
    }
    w2[idx] = f2bf(s);
}

// Dense 64->64 3x3 conv via mfma_f32_16x16x32_bf16, operand-swapped
// (A = W2 -> D rows = o-quads, D lanes = contiguous pixel cols).
// R23: packed b32 LDS staging writes (channel pairs); Bf hoist split per-s
// and staging split in 2 passes to cut peak VGPR; launch_bounds(256,3).
__global__ __launch_bounds__(256, 3) void scm_mfma(
    const float* __restrict__ x,
    const ushort* __restrict__ w2,
    const float* __restrict__ bias,
    float* __restrict__ out)
{
    __shared__ ushort xt[10 * 18 * 72];   // 25,920 B

    const int tid  = threadIdx.x;
    const int lane = tid & 63;
    const int wv   = tid >> 6;
    const int col  = lane & 15;           // A-frag m (o) / B-frag n (pixel col)
    const int g    = lane >> 4;           // k-subgroup

    // Flattened grid (1152) + bijective XCD swizzle (1152 % 8 == 0).
    const int bid = blockIdx.x;
    const int lid = (bid & 7) * 144 + (bid >> 3);
    const int b      = lid / 288;
    const int tileid = lid % 288;
    const int ti0 = (tileid / 12) * 8;    // 24 row tiles
    const int tj0 = (tileid % 12) * 16;   // 12 col tiles

    // ---- staging: spatial-lane gather, wave-sliced channels, packed b32 writes.
    {
        const int srr  = lane / 18;       // 0..2 (lanes 54..63: writes masked)
        const int scol = lane - srr * 18; // 0..17
        const bool act = lane < 54;
        int gc = tj0 + scol; if (gc > 191) gc = 191;
        int gr0 = ti0 + srr;     if (gr0 > 191) gr0 = 191;
        int gr1 = ti0 + srr + 3; if (gr1 > 191) gr1 = 191;
        int gr2 = ti0 + srr + 6; if (gr2 > 191) gr2 = 191;
        int gr3 = ti0 + srr + 9; if (gr3 > 191) gr3 = 191;

        #pragma unroll
        for (int pass = 0; pass < 2; ++pass) {
            float v[8][4];
            #pragma unroll
            for (int pj = 0; pj < 8; ++pj) {
                const int c = wv * 16 + pass * 8 + pj;
                const float* xc = x + ((size_t)(b * NCH + c)) * (HH * WW);
                v[pj][0] = xc[gr0 * WW + gc];
                v[pj][1] = xc[gr1 * WW + gc];
                v[pj][2] = xc[gr2 * WW + gc];
                v[pj][3] = xc[gr3 * WW + gc];
            }
            __builtin_amdgcn_sched_barrier(0);   // all 32 loads in flight first
            if (act) {
                #pragma unroll
                for (int pp = 0; pp < 4; ++pp) {
                    const int c = wv * 16 + pass * 8 + 2 * pp;   // even
                    uint k0 = pack2bf(v[2 * pp][0], v[2 * pp + 1][0]);
                    uint k1 = pack2bf(v[2 * pp][1], v[2 * pp + 1][1]);
                    uint k2 = pack2bf(v[2 * pp][2], v[2 * pp + 1][2]);
                    uint k3 = pack2bf(v[2 * pp][3], v[2 * pp + 1][3]);
                    *(uint*)&xt[((srr    ) * 18 + scol) * 72 + c] = k0;
                    *(uint*)&xt[((srr + 3) * 18 + scol) * 72 + c] = k1;
                    *(uint*)&xt[((srr + 6) * 18 + scol) * 72 + c] = k2;
                    if (srr == 0)
                        *(uint*)&xt[(9 * 18 + scol) * 72 + c] = k3;
                }
            }
        }
    }
    __syncthreads();

    // ---- compute (operand-swapped: acc = mfma(W2frag, xfrag, acc))
    f32x4 acc[8];
    #pragma unroll
    for (int i = 0; i < 8; ++i) acc[i] = (f32x4){0.f, 0.f, 0.f, 0.f};

    const ushort* ap0 = &xt[col * 72 + g * 8];
    const ushort* bp  = w2 + (16 * wv + col) * 576 + g * 8;

    #pragma unroll
    for (int s = 0; s < 2; ++s) {
        bf16x8 Bs[9];
        #pragma unroll
        for (int tap = 0; tap < 9; ++tap)
            Bs[tap] = *(const bf16x8*)(bp + tap * 64 + s * 32);
        #pragma unroll
        for (int kw = 0; kw < 3; ++kw) {
            bf16x8 f[10];
            #pragma unroll
            for (int R = 0; R < 10; ++R)
                f[R] = *(const bf16x8*)(ap0 + (R * 18 + kw) * 72 + s * 32);
            __builtin_amdgcn_sched_barrier(0);   // loads clustered before MFMAs
            #pragma unroll
            for (int Mt = 0; Mt < 8; ++Mt) {
                acc[Mt] = __builtin_amdgcn_mfma_f32_16x16x32_bf16(Bs[kw],     f[Mt],     acc[Mt], 0, 0, 0);
                acc[Mt] = __builtin_amdgcn_mfma_f32_16x16x32_bf16(Bs[3 + kw], f[Mt + 1], acc[Mt], 0, 0, 0);
                acc[Mt] = __builtin_amdgcn_mfma_f32_16x16x32_bf16(Bs[6 + kw], f[Mt + 2], acc[Mt], 0, 0, 0);
            }
        }
    }

    // ---- epilogue: D col = lane&15 = pixel col (contiguous); D row = o-quad.
    const int pcol = tj0 + col;
    const int obase = 16 * wv + 4 * g;
    float bv[4];
    #pragma unroll
    for (int reg = 0; reg < 4; ++reg) bv[reg] = bias[obase + reg];

    if (pcol < HOUT) {
        #pragma unroll
        for (int Mt = 0; Mt < 8; ++Mt) {
            const int row = ti0 + Mt;
            if (row < HOUT) {
                float* rp = out + ((size_t)(b * NCH + obase) * HOUT + row) * HOUT + pcol;
                #pragma unroll
                for (int reg = 0; reg < 4; ++reg)
                    rp[(size_t)reg * HOUT * HOUT] = acc[Mt][reg] + bv[reg];
            }
        }
    }
}

extern "C" void kernel_launch(void* const* d_in, const int* in_sizes, int n_in,
                              void* d_out, int out_size, void* d_ws, size_t ws_size,
                              hipStream_t stream) {
    const float* x       = (const float*)d_in[0];
    const float* weight  = (const float*)d_in[1];
    const float* bias    = (const float*)d_in[2];
    const int*   conn_in = (const int*)d_in[3];
    // d_in[4] = conn_out (implicit: k -> k/16)

    ushort* w2 = (ushort*)d_ws;   // 73,728 B

    build_w2<<<dim3((W2_N + 255) / 256), dim3(256), 0, stream>>>(weight, conn_in, w2);

    scm_mfma<<<dim3(1152), dim3(256), 0, stream>>>(x, w2, bias, (float*)d_out);
}